// Round 10
// baseline (7060.299 us; speedup 1.0000x reference)
//
#include <hip/hip_runtime.h>
#include <stdint.h>

// ---------------------------------------------------------------------------
// mLSTM block on MI355X.
// Phase A: cast x/weights to bf16; GEMM [Wx|Ax] = x @ [W_w;A_w]^T + (W_b+U_b|0)
// Phase B: persistent recurrence: 4 groups (16 batches) x 32 blocks (16 units).
//   MULTICAST-PUSH protocol (2 coherence transits): producer wave 0 packs its
//   256 h values as self-tagged u32 ((t+1)<<16 | bf16, monotone >=) and
//   multicasts the 1KB block into each of the 32 consumers' PRIVATE regions
//   (32 coalesced dwordx4 sc1 stores; no drain, no mailbox). Consumers poll
//   their own region only -- each 64B line has exactly 1 writer and 1
//   reader-thread, so no store-behind-poll-queue contention (rounds 4/8/9
//   evidence). Reload IS the poll. Two parities suffice: a block pushes t+1
//   only after it reloaded h(t), which requires every block pushed h(t),
//   which requires every block finished reading h(t-2).
//   Replay-safe: hipMemsetAsync re-zeroes tags in-graph each launch.
// ws layout (bytes):
//   0         hpush    u32[2][4][32][32][256]  8,388,608  (reuses xb region)
//   0         x_bf16   [65536][512]        67,108,864  (dead after gemm)
//   67108864  Wc_bf16  [2176][512]          2,228,224
//   69337088  bias     [2176] f32               8,704
//   69345792  U_bf16   [2048][512]          2,097,152
//   71442944  Bw_bf16  [64][512]               65,536
//   71508480  P_bf16   [512][64] (x0.1)        65,536
//   71706112  Wxc_bf16 [65536][2112]       276,824,064
// ---------------------------------------------------------------------------

typedef float    f32x4  __attribute__((ext_vector_type(4)));
typedef __bf16   bf16x8 __attribute__((ext_vector_type(8)));
typedef uint16_t u16;
typedef uint16_t u16x8  __attribute__((ext_vector_type(8)));
typedef uint32_t u32x2  __attribute__((ext_vector_type(2)));
typedef uint32_t u32x4  __attribute__((ext_vector_type(4)));

#define WS_HPUSH  0
#define WS_XB     0
#define WS_WC     67108864
#define WS_BIAS   69337088
#define WS_U      69345792
#define WS_BW     71442944
#define WS_P      71508480
#define WS_WXC    71706112

#define OUT_H     33554432
#define OUT_C     33587200

__device__ __forceinline__ u16 f2bf(float f) {
  uint32_t u = __builtin_bit_cast(uint32_t, f);
  u = (u + 0x7fffu + ((u >> 16) & 1u)) >> 16;
  return (u16)u;
}
__device__ __forceinline__ float bf2f(u16 b) {
  uint32_t u = ((uint32_t)b) << 16;
  return __builtin_bit_cast(float, u);
}
__device__ __forceinline__ f32x4 mfma16(u16x8 a, u16x8 b, f32x4 c) {
  return __builtin_amdgcn_mfma_f32_16x16x32_bf16(
      __builtin_bit_cast(bf16x8, a), __builtin_bit_cast(bf16x8, b), c, 0, 0, 0);
}
__device__ __forceinline__ float sigm(float x) { return 1.f / (1.f + __expf(-x)); }
__device__ __forceinline__ float tanh_fast(float x) {
  float a = fabsf(x);
  float e = __expf(2.f * a);
  float t = 1.f - 2.f / (e + 1.f);
  return x < 0.f ? -t : t;
}
// barrier ordering LDS only -- vmem (prefetches/pushes) stays in flight
__device__ __forceinline__ void lds_barrier() {
  asm volatile("s_waitcnt lgkmcnt(0)" ::: "memory");
  __builtin_amdgcn_sched_barrier(0);
  __builtin_amdgcn_s_barrier();
  __builtin_amdgcn_sched_barrier(0);
}

// ---------------- Phase A: casts ----------------
__global__ void cast_x(const float* __restrict__ x, u16* __restrict__ xb) {
  int i = blockIdx.x * 256 + threadIdx.x;
  const float4* src = (const float4*)x;
  float4 a = src[(size_t)i * 2];
  float4 b = src[(size_t)i * 2 + 1];
  u16x8 o;
  o[0] = f2bf(a.x); o[1] = f2bf(a.y); o[2] = f2bf(a.z); o[3] = f2bf(a.w);
  o[4] = f2bf(b.x); o[5] = f2bf(b.y); o[6] = f2bf(b.z); o[7] = f2bf(b.w);
  *(u16x8*)(xb + (size_t)i * 8) = o;
}

__global__ void prep(const float* __restrict__ W_w, const float* __restrict__ W_b,
                     const float* __restrict__ U_w, const float* __restrict__ U_b,
                     const float* __restrict__ A_w, const float* __restrict__ B_w,
                     const float* __restrict__ P_w,
                     u16* __restrict__ Wc, float* __restrict__ bias,
                     u16* __restrict__ Ubf, u16* __restrict__ Bwbf,
                     u16* __restrict__ Pbf) {
  const int total = 1114112 + 1048576 + 32768 + 32768 + 2176;
  for (int i = blockIdx.x * blockDim.x + threadIdx.x; i < total;
       i += gridDim.x * blockDim.x) {
    int idx = i;
    if (idx < 1114112) {                            // Wc [2176][512]
      int row = idx >> 9, k = idx & 511;
      float v = 0.f;
      if (row < 2048) v = W_w[row * 512 + k];
      else if (row < 2112) v = A_w[(row - 2048) * 512 + k];
      Wc[idx] = f2bf(v);
      continue;
    }
    idx -= 1114112;
    if (idx < 1048576) { Ubf[idx] = f2bf(U_w[idx]); continue; }
    idx -= 1048576;
    if (idx < 32768) { Bwbf[idx] = f2bf(B_w[idx]); continue; }
    idx -= 32768;
    if (idx < 32768) { Pbf[idx] = f2bf(0.1f * P_w[idx]); continue; }
    idx -= 32768;
    bias[idx] = (idx < 2048) ? (W_b[idx] + U_b[idx]) : 0.f;
  }
}

// ---------------- Phase A: big GEMM ----------------
__global__ void __launch_bounds__(256) gemm_wxc(const u16* __restrict__ xb,
                                                const u16* __restrict__ Wc,
                                                const float* __restrict__ bias,
                                                u16* __restrict__ outWx) {
  __shared__ u16 Atile[128 * 64];
  __shared__ u16 Btile[128 * 64];
  const int n0 = blockIdx.x * 128;
  const int m0 = blockIdx.y * 128;
  const int tid = threadIdx.x, ln = tid & 63, wv = tid >> 6;
  const int wm = (wv >> 1) * 64, wn = (wv & 1) * 64;
  f32x4 acc[4][4] = {};

  for (int k0 = 0; k0 < 512; k0 += 64) {
    __syncthreads();
    #pragma unroll
    for (int q = 0; q < 4; ++q) {
      int idx = tid + q * 256;
      int row = idx >> 3, kc = idx & 7;
      uint4 va = *(const uint4*)(xb + (size_t)(m0 + row) * 512 + k0 + kc * 8);
      *(uint4*)((char*)Atile + row * 128 + ((kc * 16) ^ ((row & 7) << 4))) = va;
      uint4 vb = *(const uint4*)(Wc + (size_t)(n0 + row) * 512 + k0 + kc * 8);
      *(uint4*)((char*)Btile + row * 128 + ((kc * 16) ^ ((row & 7) << 4))) = vb;
    }
    __syncthreads();
    #pragma unroll
    for (int kk = 0; kk < 64; kk += 32) {
      u16x8 af[4], bf[4];
      const int kb = kk * 2 + ((ln >> 4) << 4);
      #pragma unroll
      for (int i = 0; i < 4; ++i) {
        int arow = wm + i * 16 + (ln & 15);
        af[i] = *(const u16x8*)((char*)Atile + arow * 128 + (kb ^ ((arow & 7) << 4)));
        int brow = wn + i * 16 + (ln & 15);
        bf[i] = *(const u16x8*)((char*)Btile + brow * 128 + (kb ^ ((brow & 7) << 4)));
      }
      #pragma unroll
      for (int i = 0; i < 4; ++i)
        #pragma unroll
        for (int j = 0; j < 4; ++j)
          acc[i][j] = mfma16(af[i], bf[j], acc[i][j]);
    }
  }
  #pragma unroll
  for (int i = 0; i < 4; ++i) {
    const int mrow = m0 + wm + i * 16 + ((ln >> 4) << 2);
    #pragma unroll
    for (int j = 0; j < 4; ++j) {
      const int n = n0 + wn + j * 16 + (ln & 15);
      if (n < 2112) {
        const float bv = bias[n];
        #pragma unroll
        for (int r = 0; r < 4; ++r)
          outWx[(size_t)(mrow + r) * 2112 + n] = f2bf(acc[i][j][r] + bv);
      }
    }
  }
}

// ---------------- Phase B: persistent recurrence ----------------
__global__ void __launch_bounds__(512, 2) recurrent(const u16* __restrict__ Wxc,
                                                    const u16* __restrict__ Ubf,
                                                    const u16* __restrict__ Bwbf,
                                                    const u16* __restrict__ Pbf,
                                                    uint32_t* __restrict__ hpush,
                                                    float* __restrict__ out) {
  __shared__ char     h_lds[16 * 1024];   // [16 batches][512] bf16, swizzled
  __shared__ float    v_buf[16 * 68];     // [16 batches][64 r (+4 pad)]
  __shared__ float    g_buf[4 * 16 * 17]; // [4 gates][16 batches][16 u (+1)]
  __shared__ uint32_t hpub[16 * 16];      // producer pack [16 b][16 u] tagged

  const int tid = threadIdx.x;
  const int wv = tid >> 6, ln = tid & 63;
  const int grp = blockIdx.x & 3;         // 4 groups x 16 batches
  const int ublk = blockIdx.x >> 2;       // 32 unit-blocks x 16 units
  const int u0 = ublk << 4, b0 = grp << 4;

  // persistent B-operand fragments (loaded once)
  u16x8 bfrag[16];
  {
    const u16* src = (wv < 4)
        ? (Ubf + (size_t)(wv * 512 + u0 + (ln & 15)) * 512)
        : (Bwbf + (size_t)((wv - 4) * 16 + (ln & 15)) * 512);
    #pragma unroll
    for (int ks = 0; ks < 16; ++ks)
      bfrag[ks] = *(const u16x8*)(src + ks * 32 + ((ln >> 4) << 3));
  }
  u16x8 pfrag[2];
  #pragma unroll
  for (int ks = 0; ks < 2; ++ks)
    pfrag[ks] = *(const u16x8*)(Pbf + (size_t)(u0 + (ln & 15)) * 64 + ks * 32 + ((ln >> 4) << 3));

  for (int i = tid; i < 1024; i += 512)
    ((u32x4*)h_lds)[i] = (u32x4){0u, 0u, 0u, 0u};
  __syncthreads();

  const int arow_base = (ln & 15) * 1024;
  const int a_xor = (ln & 7) << 4;
  const int a_k0 = (ln >> 4) << 4;

  // reload-as-poll assignment: thread owns one 64B line of its own region
  const int r_prod = tid >> 4;             // producer slot 0..31
  const int r_row = tid & 15;              // batch row 0..15

  // one-step-ahead register prefetch state (batch = b0 + (ln>>4)*4 + j)
  uint32_t wx_cur[4] = {0, 0, 0, 0};
  u16x8 ax0_cur = {}, ax1_cur = {};
  {
    if (wv < 4) {
      const int col = wv * 512 + u0 + (ln & 15);
      const size_t rbase = ((size_t)(b0 + ((ln >> 4) << 2)) * 1024 + 0) * 2112;
      #pragma unroll
      for (int j = 0; j < 4; ++j) wx_cur[j] = Wxc[rbase + (size_t)j * 1024 * 2112 + col];
    }
    if (wv == 0) {
      const u16* axp = Wxc + ((size_t)(b0 + (ln & 15)) * 1024 + 0) * 2112 + 2048 + ((ln >> 4) << 3);
      ax0_cur = *(const u16x8*)(axp);
      ax1_cur = *(const u16x8*)(axp + 32);
    }
  }

  float c_reg[4] = {0.f, 0.f, 0.f, 0.f};
  float h_last[4] = {0.f, 0.f, 0.f, 0.f};

  #pragma unroll 1
  for (int t = 0; t < 1024; ++t) {
    // phase 1: K-loop MFMA; A = h_{t-1} [16x512] from LDS
    f32x4 acc0 = {0.f, 0.f, 0.f, 0.f}, acc1 = {0.f, 0.f, 0.f, 0.f};
    #pragma unroll
    for (int ks = 0; ks < 16; ks += 2) {
      u16x8 a0 = *(const u16x8*)(h_lds + arow_base + ((ks * 64 + a_k0) ^ a_xor));
      u16x8 a1 = *(const u16x8*)(h_lds + arow_base + (((ks + 1) * 64 + a_k0) ^ a_xor));
      acc0 = mfma16(a0, bfrag[ks], acc0);
      acc1 = mfma16(a1, bfrag[ks + 1], acc1);
    }
    const f32x4 acc = acc0 + acc1;

    // phase 2: v / gates to LDS
    if (wv >= 4) {
      const int r = ((wv - 4) << 4) + (ln & 15);
      const int br = (ln >> 4) << 2;
      #pragma unroll
      for (int j = 0; j < 4; ++j) v_buf[(br + j) * 68 + r] = acc[j];
    } else {
      const int gi = wv * 272 + (ln & 15);
      const int br = (ln >> 4) << 2;
      #pragma unroll
      for (int j = 0; j < 4; ++j) {
        float g = acc[j] + bf2f((u16)wx_cur[j]);
        g = (wv == 3) ? tanh_fast(g) : sigm(g);
        g_buf[gi + (br + j) * 17] = g;
      }
    }
    lds_barrier();                          // B1

    // phase 3 (wave 0): mix MFMA + cell update + tagged multicast push
    if (wv == 0) {
      __builtin_amdgcn_s_setprio(1);
      f32x4 accm = {0.f, 0.f, 0.f, 0.f};
      const int bb = ln & 15;
      const int r0 = (ln >> 4) << 3;
      u16x8 af;
      #pragma unroll
      for (int i = 0; i < 8; ++i)
        af[i] = f2bf(bf2f(ax0_cur[i]) * v_buf[bb * 68 + r0 + i]);
      accm = mfma16(af, pfrag[0], accm);
      #pragma unroll
      for (int i = 0; i < 8; ++i)
        af[i] = f2bf(bf2f(ax1_cur[i]) * v_buf[bb * 68 + 32 + r0 + i]);
      accm = mfma16(af, pfrag[1], accm);
      // accm[j] = mix[batch=(ln>>4)*4+j][unit=ln&15] -- register-aligned
      const int u = ln & 15;
      const int brb = (ln >> 4) * 4;
      float hv[4];
      #pragma unroll
      for (int j = 0; j < 4; ++j) {
        const int go = (brb + j) * 17 + u;
        float iv = g_buf[go];
        float fv = g_buf[272 + go];
        float ov = g_buf[544 + go];
        float gv = g_buf[816 + go];
        c_reg[j] = fv * c_reg[j] + iv * gv + accm[j];   // 0.1 folded into P
        hv[j] = ov * tanh_fast(c_reg[j]);
        h_last[j] = hv[j];
      }
      if (t < 1023) {
        const uint32_t tagv = ((uint32_t)(t + 1)) << 16;
        #pragma unroll
        for (int j = 0; j < 4; ++j)
          hpub[(brb + j) * 16 + u] = tagv | (uint32_t)f2bf(hv[j]);
        asm volatile("s_waitcnt lgkmcnt(0)" ::: "memory");
        __builtin_amdgcn_sched_barrier(0);
        u32x4 pv = *(const u32x4*)&hpub[(ln >> 2) * 16 + (ln & 3) * 4];
        // multicast: one coalesced 1KB store per consumer region
        uint32_t* dst = hpush + (size_t)(((t & 1) * 4 + grp) * 32) * 8192
                        + (size_t)ublk * 256 + (ln >> 2) * 16 + (ln & 3) * 4;
        #pragma unroll
        for (int c = 0; c < 32; ++c) {
          asm volatile("global_store_dwordx4 %0, %1, off sc1"
                       :: "v"(dst), "v"(pv) : "memory");
          dst += 8192;
        }
      }
      __builtin_amdgcn_s_setprio(0);
      #pragma unroll
      for (int j = 0; j < 4; ++j)                         // outs off crit path
        out[((size_t)(b0 + brb + j) * 1024 + t) * 512 + u0 + u] = hv[j];
      {
        const int tn = (t < 1023) ? t + 1 : 1023;         // wave-0 prefetch
        const u16* axp = Wxc + ((size_t)(b0 + (ln & 15)) * 1024 + tn) * 2112 + 2048 + ((ln >> 4) << 3);
        ax0_cur = *(const u16x8*)(axp);
        ax1_cur = *(const u16x8*)(axp + 32);
        const int col = u0 + (ln & 15);
        const size_t rbase = ((size_t)(b0 + ((ln >> 4) << 2)) * 1024 + tn) * 2112;
        #pragma unroll
        for (int j = 0; j < 4; ++j) wx_cur[j] = Wxc[rbase + (size_t)j * 1024 * 2112 + col];
      }
    } else if (wv < 4) {
      // waves 1-3: prefetch before polling (overlaps poll RTT)
      const int tn = (t < 1023) ? t + 1 : 1023;
      const int col = wv * 512 + u0 + (ln & 15);
      const size_t rbase = ((size_t)(b0 + ((ln >> 4) << 2)) * 1024 + tn) * 2112;
      #pragma unroll
      for (int j = 0; j < 4; ++j) wx_cur[j] = Wxc[rbase + (size_t)j * 1024 * 2112 + col];
    }

    if (t < 1023) {
      // phase 4: reload-as-poll of OWN private region (1 writer/1 reader per
      // line). 4x dwordx4 sc1 + one vmcnt(0); per-lane retry via exec mask.
      const uint32_t tg = (uint32_t)(t + 1);
      const uint32_t* p = hpush + ((size_t)(((t & 1) * 4 + grp) * 32 + ublk)) * 8192
                          + r_prod * 256 + r_row * 16;
      u32x4 A, B, C, D;
      bool ok = false;
      while (!ok) {
        asm volatile(
            "global_load_dwordx4 %0, %4, off sc1\n\t"
            "global_load_dwordx4 %1, %4, off offset:16 sc1\n\t"
            "global_load_dwordx4 %2, %4, off offset:32 sc1\n\t"
            "global_load_dwordx4 %3, %4, off offset:48 sc1\n\t"
            "s_waitcnt vmcnt(0)"
            : "=&v"(A), "=&v"(B), "=&v"(C), "=&v"(D)
            : "v"(p)
            : "memory");
        ok = (A[0] >> 16) >= tg && (A[1] >> 16) >= tg &&
             (A[2] >> 16) >= tg && (A[3] >> 16) >= tg &&
             (B[0] >> 16) >= tg && (B[1] >> 16) >= tg &&
             (B[2] >> 16) >= tg && (B[3] >> 16) >= tg &&
             (C[0] >> 16) >= tg && (C[1] >> 16) >= tg &&
             (C[2] >> 16) >= tg && (C[3] >> 16) >= tg &&
             (D[0] >> 16) >= tg && (D[1] >> 16) >= tg &&
             (D[2] >> 16) >= tg && (D[3] >> 16) >= tg;
      }
      // strip tags -> swizzled LDS row r_row, units r_prod*16 + k*4..
      #pragma unroll
      for (int k = 0; k < 4; ++k) {
        u32x4 v = (k == 0) ? A : (k == 1) ? B : (k == 2) ? C : D;
        u32x2 w;
        w[0] = (v[0] & 0xffffu) | (v[1] << 16);
        w[1] = (v[2] & 0xffffu) | (v[3] << 16);
        const int byte = r_row * 1024 + ((r_prod * 32 + k * 8) ^ ((r_row & 7) << 4));
        *(u32x2*)(h_lds + byte) = w;
      }
    }
    lds_barrier();                          // B2
  }

  if (wv == 0) {
    const int u = ln & 15, brb = (ln >> 4) * 4;
    #pragma unroll
    for (int j = 0; j < 4; ++j) {
      out[OUT_H + (size_t)(b0 + brb + j) * 512 + u0 + u] = h_last[j];
      out[OUT_C + (size_t)(b0 + brb + j) * 512 + u0 + u] = c_reg[j];
    }
  }
}

// ---------------------------------------------------------------------------
extern "C" void kernel_launch(void* const* d_in, const int* in_sizes, int n_in,
                              void* d_out, int out_size, void* d_ws, size_t ws_size,
                              hipStream_t stream) {
  const float* x   = (const float*)d_in[0];
  const float* W_w = (const float*)d_in[1];
  const float* W_b = (const float*)d_in[2];
  const float* U_w = (const float*)d_in[3];
  const float* U_b = (const float*)d_in[4];
  const float* A_w = (const float*)d_in[5];
  const float* B_w = (const float*)d_in[6];
  const float* P_w = (const float*)d_in[7];
  char* ws = (char*)d_ws;

  u16*      xb    = (u16*)(ws + WS_XB);
  u16*      Wc    = (u16*)(ws + WS_WC);
  float*    bias  = (float*)(ws + WS_BIAS);
  u16*      Ubf   = (u16*)(ws + WS_U);
  u16*      Bwbf  = (u16*)(ws + WS_BW);
  u16*      Pbf   = (u16*)(ws + WS_P);
  uint32_t* hpush = (uint32_t*)(ws + WS_HPUSH);   // reuses xb region post-GEMM
  u16*      Wxc   = (u16*)(ws + WS_WXC);
  float*    outp  = (float*)d_out;

  cast_x<<<16384, 256, 0, stream>>>(x, xb);
  prep<<<2048, 256, 0, stream>>>(W_w, W_b, U_w, U_b, A_w, B_w, P_w,
                                 Wc, bias, Ubf, Bwbf, Pbf);
  gemm_wxc<<<dim3(17, 512), 256, 0, stream>>>(xb, Wc, bias, Wxc);
  // xb is dead after the GEMM; re-zero the tag region in-graph (replay-safe).
  hipMemsetAsync(hpush, 0, 8388608, stream);

  void* args[] = { &Wxc, &Ubf, &Bwbf, &Pbf, &hpush, &outp };
  hipError_t e = hipLaunchCooperativeKernel((const void*)recurrent, dim3(128),
                                            dim3(512), args, 0, stream);
  if (e != hipSuccess) {
    // 128 blocks / 256 CUs: co-resident even with a plain launch.
    recurrent<<<dim3(128), dim3(512), 0, stream>>>(Wxc, Ubf, Bwbf, Pbf,
                                                   hpush, outp);
  }
}

// Round 11
// 5395.591 us; speedup vs baseline: 1.3085x; 1.3085x over previous
//
#include <hip/hip_runtime.h>
#include <stdint.h>

// ---------------------------------------------------------------------------
// mLSTM block on MI355X.
// Phase A: cast x/weights to bf16; GEMM [Wx|Ax] = x @ [W_w;A_w]^T + (W_b+U_b|0)
// Phase B: persistent recurrence with TWO-GROUP INTERLEAVE: 64 blocks; block
//   (pair=bid>>5, cblk=bid&31) owns 16 units (u0=cblk*16) for BOTH groups
//   {2*pair, 2*pair+1} (16 batches each). While group 0's h transits the
//   fabric, the block computes group 1's step -- sync latency amortized over
//   2 steps. Producer waves: wave0 (g0), wave4 (g1). Wave1 polls.
//   Exchange = round-9 verified protocol: relaxed agent(sc1) h stores +
//   vmcnt(0) drain + per-consumer private mailbox lines (monotone >=,
//   parity double-buffer, in-graph mbox re-zero). Round-10 lesson: sc1
//   stores write through IC to HBM -- no data replication (multicast killed).
//   Reload(g0) is issue-early/wait-late so its RTT overlaps poll(g1).
// ws layout (bytes): same as round 9.
//   0         x_bf16   [65536][512]        67,108,864
//   67108864  Wc_bf16  [2176][512]          2,228,224
//   69337088  bias     [2176] f32               8,704
//   69345792  U_bf16   [2048][512]          2,097,152
//   71442944  Bw_bf16  [64][512]               65,536
//   71508480  P_bf16   [512][64] (x0.1)        65,536
//   71574016  hbuf     [2][64][512] bf16      131,072
//   71705088  mbox     u32[4][32][32]          16,384
//   71721472  Wxc_bf16 [65536][2112]       276,824,064
// ---------------------------------------------------------------------------

typedef float    f32x4  __attribute__((ext_vector_type(4)));
typedef __bf16   bf16x8 __attribute__((ext_vector_type(8)));
typedef uint16_t u16;
typedef uint16_t u16x8  __attribute__((ext_vector_type(8)));
typedef uint32_t u32x4  __attribute__((ext_vector_type(4)));

#define WS_XB     0
#define WS_WC     67108864
#define WS_BIAS   69337088
#define WS_U      69345792
#define WS_BW     71442944
#define WS_P      71508480
#define WS_HBUF   71574016
#define WS_MBOX   71705088
#define WS_WXC    71721472

#define OUT_H     33554432
#define OUT_C     33587200

__device__ __forceinline__ u16 f2bf(float f) {
  uint32_t u = __builtin_bit_cast(uint32_t, f);
  u = (u + 0x7fffu + ((u >> 16) & 1u)) >> 16;
  return (u16)u;
}
__device__ __forceinline__ float bf2f(u16 b) {
  uint32_t u = ((uint32_t)b) << 16;
  return __builtin_bit_cast(float, u);
}
__device__ __forceinline__ f32x4 mfma16(u16x8 a, u16x8 b, f32x4 c) {
  return __builtin_amdgcn_mfma_f32_16x16x32_bf16(
      __builtin_bit_cast(bf16x8, a), __builtin_bit_cast(bf16x8, b), c, 0, 0, 0);
}
__device__ __forceinline__ float sigm(float x) { return 1.f / (1.f + __expf(-x)); }
__device__ __forceinline__ float tanh_fast(float x) {
  float a = fabsf(x);
  float e = __expf(2.f * a);
  float t = 1.f - 2.f / (e + 1.f);
  return x < 0.f ? -t : t;
}
// barrier ordering LDS only -- vmem (prefetches, early reloads) stays in flight
__device__ __forceinline__ void lds_barrier() {
  asm volatile("s_waitcnt lgkmcnt(0)" ::: "memory");
  __builtin_amdgcn_sched_barrier(0);
  __builtin_amdgcn_s_barrier();
  __builtin_amdgcn_sched_barrier(0);
}

// ---------------- Phase A: casts ----------------
__global__ void cast_x(const float* __restrict__ x, u16* __restrict__ xb) {
  int i = blockIdx.x * 256 + threadIdx.x;
  const float4* src = (const float4*)x;
  float4 a = src[(size_t)i * 2];
  float4 b = src[(size_t)i * 2 + 1];
  u16x8 o;
  o[0] = f2bf(a.x); o[1] = f2bf(a.y); o[2] = f2bf(a.z); o[3] = f2bf(a.w);
  o[4] = f2bf(b.x); o[5] = f2bf(b.y); o[6] = f2bf(b.z); o[7] = f2bf(b.w);
  *(u16x8*)(xb + (size_t)i * 8) = o;
}

__global__ void prep(const float* __restrict__ W_w, const float* __restrict__ W_b,
                     const float* __restrict__ U_w, const float* __restrict__ U_b,
                     const float* __restrict__ A_w, const float* __restrict__ B_w,
                     const float* __restrict__ P_w,
                     u16* __restrict__ Wc, float* __restrict__ bias,
                     u16* __restrict__ Ubf, u16* __restrict__ Bwbf,
                     u16* __restrict__ Pbf, uint32_t* __restrict__ mbox) {
  const int total = 1114112 + 1048576 + 32768 + 32768 + 2176 + 4096;
  for (int i = blockIdx.x * blockDim.x + threadIdx.x; i < total;
       i += gridDim.x * blockDim.x) {
    int idx = i;
    if (idx < 1114112) {                            // Wc [2176][512]
      int row = idx >> 9, k = idx & 511;
      float v = 0.f;
      if (row < 2048) v = W_w[row * 512 + k];
      else if (row < 2112) v = A_w[(row - 2048) * 512 + k];
      Wc[idx] = f2bf(v);
      continue;
    }
    idx -= 1114112;
    if (idx < 1048576) { Ubf[idx] = f2bf(U_w[idx]); continue; }
    idx -= 1048576;
    if (idx < 32768) { Bwbf[idx] = f2bf(B_w[idx]); continue; }
    idx -= 32768;
    if (idx < 32768) { Pbf[idx] = f2bf(0.1f * P_w[idx]); continue; }
    idx -= 32768;
    if (idx < 2176) {
      bias[idx] = (idx < 2048) ? (W_b[idx] + U_b[idx]) : 0.f;
      continue;
    }
    idx -= 2176;
    mbox[idx] = 0;                                  // epochs (monotone >=)
  }
}

// ---------------- Phase A: big GEMM ----------------
__global__ void __launch_bounds__(256) gemm_wxc(const u16* __restrict__ xb,
                                                const u16* __restrict__ Wc,
                                                const float* __restrict__ bias,
                                                u16* __restrict__ outWx) {
  __shared__ u16 Atile[128 * 64];
  __shared__ u16 Btile[128 * 64];
  const int n0 = blockIdx.x * 128;
  const int m0 = blockIdx.y * 128;
  const int tid = threadIdx.x, ln = tid & 63, wv = tid >> 6;
  const int wm = (wv >> 1) * 64, wn = (wv & 1) * 64;
  f32x4 acc[4][4] = {};

  for (int k0 = 0; k0 < 512; k0 += 64) {
    __syncthreads();
    #pragma unroll
    for (int q = 0; q < 4; ++q) {
      int idx = tid + q * 256;
      int row = idx >> 3, kc = idx & 7;
      uint4 va = *(const uint4*)(xb + (size_t)(m0 + row) * 512 + k0 + kc * 8);
      *(uint4*)((char*)Atile + row * 128 + ((kc * 16) ^ ((row & 7) << 4))) = va;
      uint4 vb = *(const uint4*)(Wc + (size_t)(n0 + row) * 512 + k0 + kc * 8);
      *(uint4*)((char*)Btile + row * 128 + ((kc * 16) ^ ((row & 7) << 4))) = vb;
    }
    __syncthreads();
    #pragma unroll
    for (int kk = 0; kk < 64; kk += 32) {
      u16x8 af[4], bf[4];
      const int kb = kk * 2 + ((ln >> 4) << 4);
      #pragma unroll
      for (int i = 0; i < 4; ++i) {
        int arow = wm + i * 16 + (ln & 15);
        af[i] = *(const u16x8*)((char*)Atile + arow * 128 + (kb ^ ((arow & 7) << 4)));
        int brow = wn + i * 16 + (ln & 15);
        bf[i] = *(const u16x8*)((char*)Btile + brow * 128 + (kb ^ ((brow & 7) << 4)));
      }
      #pragma unroll
      for (int i = 0; i < 4; ++i)
        #pragma unroll
        for (int j = 0; j < 4; ++j)
          acc[i][j] = mfma16(af[i], bf[j], acc[i][j]);
    }
  }
  #pragma unroll
  for (int i = 0; i < 4; ++i) {
    const int mrow = m0 + wm + i * 16 + ((ln >> 4) << 2);
    #pragma unroll
    for (int j = 0; j < 4; ++j) {
      const int n = n0 + wn + j * 16 + (ln & 15);
      if (n < 2112) {
        const float bv = bias[n];
        #pragma unroll
        for (int r = 0; r < 4; ++r)
          outWx[(size_t)(mrow + r) * 2112 + n] = f2bf(acc[i][j][r] + bv);
      }
    }
  }
}

// ---------------- Phase B helpers ----------------
__device__ __forceinline__ void phase1(int wv, int ln, const char* hl,
                                       float* vb, float* gb,
                                       const u16x8 (&bfrag)[16],
                                       const uint32_t (&wx)[4],
                                       int arow_base, int a_xor, int a_k0) {
  f32x4 acc0 = {0.f, 0.f, 0.f, 0.f}, acc1 = {0.f, 0.f, 0.f, 0.f};
  #pragma unroll
  for (int ks = 0; ks < 16; ks += 2) {
    u16x8 a0 = *(const u16x8*)(hl + arow_base + ((ks * 64 + a_k0) ^ a_xor));
    u16x8 a1 = *(const u16x8*)(hl + arow_base + (((ks + 1) * 64 + a_k0) ^ a_xor));
    acc0 = mfma16(a0, bfrag[ks], acc0);
    acc1 = mfma16(a1, bfrag[ks + 1], acc1);
  }
  const f32x4 acc = acc0 + acc1;
  if (wv >= 4) {
    const int r = ((wv - 4) << 4) + (ln & 15);
    const int br = (ln >> 4) << 2;
    #pragma unroll
    for (int j = 0; j < 4; ++j) vb[(br + j) * 68 + r] = acc[j];
  } else {
    const int gi = wv * 272 + (ln & 15);
    const int br = (ln >> 4) << 2;
    #pragma unroll
    for (int j = 0; j < 4; ++j) {
      float gg = acc[j] + bf2f((u16)wx[j]);
      gg = (wv == 3) ? tanh_fast(gg) : sigm(gg);
      gb[gi + (br + j) * 17] = gg;
    }
  }
}

__device__ __forceinline__ void produce_step(int t, int ln, int u0, int b0g,
                                             int cblk, int mgrp,
                                             const float* vb, const float* gb,
                                             const u16x8& ax0, const u16x8& ax1,
                                             const u16x8 (&pfrag)[2],
                                             u16* hbuf, uint32_t* mbox,
                                             float* out,
                                             float (&c_reg)[4], float (&h_last)[4]) {
  __builtin_amdgcn_s_setprio(1);
  f32x4 accm = {0.f, 0.f, 0.f, 0.f};
  const int bb = ln & 15;
  const int r0 = (ln >> 4) << 3;
  u16x8 af;
  #pragma unroll
  for (int i = 0; i < 8; ++i)
    af[i] = f2bf(bf2f(ax0[i]) * vb[bb * 68 + r0 + i]);
  accm = mfma16(af, pfrag[0], accm);
  #pragma unroll
  for (int i = 0; i < 8; ++i)
    af[i] = f2bf(bf2f(ax1[i]) * vb[bb * 68 + 32 + r0 + i]);
  accm = mfma16(af, pfrag[1], accm);
  // accm[j] = mix[batch=(ln>>4)*4+j][unit=ln&15] -- register-aligned
  const int u = ln & 15;
  const int brb = (ln >> 4) * 4;
  float hv[4];
  #pragma unroll
  for (int j = 0; j < 4; ++j) {
    const int go = (brb + j) * 17 + u;
    float iv = gb[go];
    float fv = gb[272 + go];
    float ov = gb[544 + go];
    float gv = gb[816 + go];
    c_reg[j] = fv * c_reg[j] + iv * gv + accm[j];   // 0.1 folded into P
    hv[j] = ov * tanh_fast(c_reg[j]);
    h_last[j] = hv[j];
  }
  if (t < 1023) {
    u16* hdst = hbuf + (size_t)(t & 1) * 32768;
    #pragma unroll
    for (int j = 0; j < 4; ++j)
      __hip_atomic_store(hdst + (size_t)(b0g + brb + j) * 512 + u0 + u,
                         f2bf(hv[j]), __ATOMIC_RELAXED, __HIP_MEMORY_SCOPE_AGENT);
    asm volatile("s_waitcnt vmcnt(0)" ::: "memory");  // h at coherence point
    if (ln < 32)
      __hip_atomic_store(mbox + ((size_t)mgrp * 32 + ln) * 32 + cblk,
                         (uint32_t)(t + 1), __ATOMIC_RELAXED, __HIP_MEMORY_SCOPE_AGENT);
  }
  __builtin_amdgcn_s_setprio(0);
  #pragma unroll
  for (int j = 0; j < 4; ++j)
    out[((size_t)(b0g + brb + j) * 1024 + t) * 512 + u0 + u] = hv[j];
}

// ---------------- Phase B: persistent recurrence (2-group interleave) -------
__global__ void __launch_bounds__(512, 2) recurrent(const u16* __restrict__ Wxc,
                                                    const u16* __restrict__ Ubf,
                                                    const u16* __restrict__ Bwbf,
                                                    const u16* __restrict__ Pbf,
                                                    u16* __restrict__ hbuf,
                                                    uint32_t* __restrict__ mbox,
                                                    float* __restrict__ out) {
  __shared__ char  h_lds[2][16 * 1024];   // per group: [16 b][512] bf16 swizzled
  __shared__ float v_buf[2][16 * 68];
  __shared__ float g_buf[2][4 * 16 * 17];

  const int tid = threadIdx.x;
  const int wv = tid >> 6, ln = tid & 63;
  const int pair = blockIdx.x >> 5;       // 2 pairs x 32 unit-blocks
  const int cblk = blockIdx.x & 31;
  const int u0 = cblk << 4;
  const int b0g0 = pair << 5;             // group 2*pair   batches
  const int b0g1 = b0g0 + 16;             // group 2*pair+1 batches
  const int mg0 = pair * 2, mg1 = mg0 + 1;

  // persistent B-operand fragments (loaded once; shared by both groups)
  u16x8 bfrag[16];
  {
    const u16* src = (wv < 4)
        ? (Ubf + (size_t)(wv * 512 + u0 + (ln & 15)) * 512)
        : (Bwbf + (size_t)((wv - 4) * 16 + (ln & 15)) * 512);
    #pragma unroll
    for (int ks = 0; ks < 16; ++ks)
      bfrag[ks] = *(const u16x8*)(src + ks * 32 + ((ln >> 4) << 3));
  }
  u16x8 pfrag[2];
  #pragma unroll
  for (int ks = 0; ks < 2; ++ks)
    pfrag[ks] = *(const u16x8*)(Pbf + (size_t)(u0 + (ln & 15)) * 64 + ks * 32 + ((ln >> 4) << 3));

  for (int i = tid; i < 2048; i += 512)
    ((u32x4*)h_lds)[i] = (u32x4){0u, 0u, 0u, 0u};
  __syncthreads();

  const int arow_base = (ln & 15) * 1024;
  const int a_xor = (ln & 7) << 4;
  const int a_k0 = (ln >> 4) << 4;
  const int ax_b0 = b0g0 + ((wv & 4) << 2);   // wave0 -> g0 rows, wave4 -> g1

  // one-step-ahead register prefetch state
  uint32_t wx_cur[2][4] = {};
  u16x8 ax0_cur = {}, ax1_cur = {};
  {
    if (wv < 4) {
      const int col = wv * 512 + u0 + (ln & 15);
      #pragma unroll
      for (int g2 = 0; g2 < 2; ++g2) {
        const size_t rb = ((size_t)(b0g0 + g2 * 16 + ((ln >> 4) << 2)) * 1024 + 0) * 2112;
        #pragma unroll
        for (int j = 0; j < 4; ++j)
          wx_cur[g2][j] = Wxc[rb + (size_t)j * 1024 * 2112 + col];
      }
    }
    if ((wv & 3) == 0) {
      const u16* axp = Wxc + ((size_t)(ax_b0 + (ln & 15)) * 1024 + 0) * 2112 + 2048 + ((ln >> 4) << 3);
      ax0_cur = *(const u16x8*)(axp);
      ax1_cur = *(const u16x8*)(axp + 32);
    }
  }

  float c_reg[4] = {0.f, 0.f, 0.f, 0.f};     // wave0: g0 cells; wave4: g1 cells
  float h_last[4] = {0.f, 0.f, 0.f, 0.f};

  #pragma unroll 1
  for (int t = 0; t < 1024; ++t) {
    // ---- compute g0
    phase1(wv, ln, h_lds[0], v_buf[0], g_buf[0], bfrag, wx_cur[0],
           arow_base, a_xor, a_k0);
    lds_barrier();                                        // B1
    if (wv == 0)
      produce_step(t, ln, u0, b0g0, cblk, mg0, v_buf[0], g_buf[0],
                   ax0_cur, ax1_cur, pfrag, hbuf, mbox, out, c_reg, h_last);
    // ---- compute g1 (overlaps g0's h transit)
    phase1(wv, ln, h_lds[1], v_buf[1], g_buf[1], bfrag, wx_cur[1],
           arow_base, a_xor, a_k0);
    lds_barrier();                                        // B2
    if (wv == 4)
      produce_step(t, ln, u0, b0g1, cblk, mg1, v_buf[1], g_buf[1],
                   ax0_cur, ax1_cur, pfrag, hbuf, mbox, out, c_reg, h_last);
    if (wv == 1 && t < 1023) {
      uint32_t* fp = mbox + ((size_t)mg0 * 32 + cblk) * 32 + (ln & 31);
      const uint32_t target = (uint32_t)(t + 1);
      while (true) {
        uint32_t f = __hip_atomic_load(fp, __ATOMIC_RELAXED, __HIP_MEMORY_SCOPE_AGENT);
        if (__ballot(f >= target) == ~0ull) break;
      }
    }
    lds_barrier();                                        // B3 (g0 confirmed)

    if (t < 1023) {
      // issue reload(g0) EARLY (wait after B4 -- RTT overlaps poll(g1))
      const int row0 = tid >> 6, kc = tid & 63;
      const u16* base0 = hbuf + (size_t)(t & 1) * 32768 + (size_t)(b0g0) * 512 + kc * 8;
      const u16* p0 = base0 + (size_t)row0 * 512;
      const u16* p1 = base0 + (size_t)(row0 + 8) * 512;
      u32x4 r0a, r0b;
      asm volatile(
          "global_load_dwordx4 %0, %2, off sc1\n\t"
          "global_load_dwordx4 %1, %3, off sc1"
          : "=&v"(r0a), "=&v"(r0b) : "v"(p0), "v"(p1) : "memory");

      // prefetch Wx/Ax for t+1 (stays in flight across barriers)
      {
        const int tn = t + 1;
        if (wv < 4) {
          const int col = wv * 512 + u0 + (ln & 15);
          #pragma unroll
          for (int g2 = 0; g2 < 2; ++g2) {
            const size_t rb = ((size_t)(b0g0 + g2 * 16 + ((ln >> 4) << 2)) * 1024 + tn) * 2112;
            #pragma unroll
            for (int j = 0; j < 4; ++j)
              wx_cur[g2][j] = Wxc[rb + (size_t)j * 1024 * 2112 + col];
          }
        }
        if ((wv & 3) == 0) {
          const u16* axp = Wxc + ((size_t)(ax_b0 + (ln & 15)) * 1024 + tn) * 2112 + 2048 + ((ln >> 4) << 3);
          ax0_cur = *(const u16x8*)(axp);
          ax1_cur = *(const u16x8*)(axp + 32);
        }
      }

      if (wv == 1) {                       // poll g1 (overlaps reload0 flight)
        uint32_t* fp = mbox + ((size_t)mg1 * 32 + cblk) * 32 + (ln & 31);
        const uint32_t target = (uint32_t)(t + 1);
        while (true) {
          uint32_t f = __hip_atomic_load(fp, __ATOMIC_RELAXED, __HIP_MEMORY_SCOPE_AGENT);
          if (__ballot(f >= target) == ~0ull) break;
        }
      }
      lds_barrier();                                      // B4 (g1 confirmed)

      // land reload(g0) -> h_lds[0]
      asm volatile("s_waitcnt vmcnt(0)" ::: "memory");
      __builtin_amdgcn_sched_barrier(0);
      *(u32x4*)(h_lds[0] + row0 * 1024 + ((kc * 16) ^ ((row0 & 7) << 4))) = r0a;
      *(u32x4*)(h_lds[0] + (row0 + 8) * 1024 + ((kc * 16) ^ (((row0 + 8) & 7) << 4))) = r0b;

      // reload(g1): issue + wait + land
      const u16* base1 = hbuf + (size_t)(t & 1) * 32768 + (size_t)(b0g1) * 512 + kc * 8;
      const u16* q0 = base1 + (size_t)row0 * 512;
      const u16* q1 = base1 + (size_t)(row0 + 8) * 512;
      u32x4 r1a, r1b;
      asm volatile(
          "global_load_dwordx4 %0, %2, off sc1\n\t"
          "global_load_dwordx4 %1, %3, off sc1\n\t"
          "s_waitcnt vmcnt(0)"
          : "=&v"(r1a), "=&v"(r1b) : "v"(q0), "v"(q1) : "memory");
      __builtin_amdgcn_sched_barrier(0);
      *(u32x4*)(h_lds[1] + row0 * 1024 + ((kc * 16) ^ ((row0 & 7) << 4))) = r1a;
      *(u32x4*)(h_lds[1] + (row0 + 8) * 1024 + ((kc * 16) ^ (((row0 + 8) & 7) << 4))) = r1b;
      lds_barrier();                                      // B5
    }
  }

  if (wv == 0) {
    const int u = ln & 15, brb = (ln >> 4) * 4;
    #pragma unroll
    for (int j = 0; j < 4; ++j) {
      out[OUT_H + (size_t)(b0g0 + brb + j) * 512 + u0 + u] = h_last[j];
      out[OUT_C + (size_t)(b0g0 + brb + j) * 512 + u0 + u] = c_reg[j];
    }
  } else if (wv == 4) {
    const int u = ln & 15, brb = (ln >> 4) * 4;
    #pragma unroll
    for (int j = 0; j < 4; ++j) {
      out[OUT_H + (size_t)(b0g1 + brb + j) * 512 + u0 + u] = h_last[j];
      out[OUT_C + (size_t)(b0g1 + brb + j) * 512 + u0 + u] = c_reg[j];
    }
  }
}

// ---------------------------------------------------------------------------
extern "C" void kernel_launch(void* const* d_in, const int* in_sizes, int n_in,
                              void* d_out, int out_size, void* d_ws, size_t ws_size,
                              hipStream_t stream) {
  const float* x   = (const float*)d_in[0];
  const float* W_w = (const float*)d_in[1];
  const float* W_b = (const float*)d_in[2];
  const float* U_w = (const float*)d_in[3];
  const float* U_b = (const float*)d_in[4];
  const float* A_w = (const float*)d_in[5];
  const float* B_w = (const float*)d_in[6];
  const float* P_w = (const float*)d_in[7];
  char* ws = (char*)d_ws;

  u16*      xb   = (u16*)(ws + WS_XB);
  u16*      Wc   = (u16*)(ws + WS_WC);
  float*    bias = (float*)(ws + WS_BIAS);
  u16*      Ubf  = (u16*)(ws + WS_U);
  u16*      Bwbf = (u16*)(ws + WS_BW);
  u16*      Pbf  = (u16*)(ws + WS_P);
  u16*      hbuf = (u16*)(ws + WS_HBUF);
  uint32_t* mbox = (uint32_t*)(ws + WS_MBOX);
  u16*      Wxc  = (u16*)(ws + WS_WXC);
  float*    outp = (float*)d_out;

  cast_x<<<16384, 256, 0, stream>>>(x, xb);
  prep<<<2048, 256, 0, stream>>>(W_w, W_b, U_w, U_b, A_w, B_w, P_w,
                                 Wc, bias, Ubf, Bwbf, Pbf, mbox);
  gemm_wxc<<<dim3(17, 512), 256, 0, stream>>>(xb, Wc, bias, Wxc);

  void* args[] = { &Wxc, &Ubf, &Bwbf, &Pbf, &hbuf, &mbox, &outp };
  hipError_t e = hipLaunchCooperativeKernel((const void*)recurrent, dim3(64),
                                            dim3(512), args, 0, stream);
  if (e != hipSuccess) {
    // 64 blocks / 256 CUs: co-resident even with a plain launch.
    recurrent<<<dim3(64), dim3(512), 0, stream>>>(Wxc, Ubf, Bwbf, Pbf,
                                                  hbuf, mbox, outp);
  }
}

// Round 12
// 4176.170 us; speedup vs baseline: 1.6906x; 1.2920x over previous
//
#include <hip/hip_runtime.h>
#include <stdint.h>

// ---------------------------------------------------------------------------
// mLSTM block on MI355X.
// Phase A: cast x/weights to bf16; GEMM [Wx|Ax] = x @ [W_w;A_w]^T + (W_b+U_b|0)
// Phase B: persistent recurrence: 4 groups (16 batches) x 32 blocks (16 units),
//   128 blocks. Round-9 verified protocol (relaxed agent sc1 h stores +
//   vmcnt(0) drain + per-consumer private mailbox lines, monotone >=, parity
//   double-buffer, in-graph mbox re-zero) with three latency cuts:
//   (1) block-major hbuf: publish = ONE coalesced 512B dwordx4 sc1 store
//       (via LDS transpose) instead of 4 scattered stores; reload coalesced.
//   (2) waves 1-3 all poll own mailbox line; first observer posts epoch to an
//       LDS word others early-exit on (discovery ~R/4 instead of ~R/2).
//   (3) ALL Wx/Ax prefetches issue after the reload vmcnt(0) -- no forced
//       drain of in-flight prefetches anywhere in the step.
// ws layout (bytes):
//   0         x_bf16   [65536][512]        67,108,864
//   67108864  Wc_bf16  [2176][512]          2,228,224
//   69337088  bias     [2176] f32               8,704
//   69345792  U_bf16   [2048][512]          2,097,152
//   71442944  Bw_bf16  [64][512]               65,536
//   71508480  P_bf16   [512][64] (x0.1)        65,536
//   71574016  hbuf     [2][4][32][256] u16    131,072   (block-major)
//   71705088  mbox     u32[4][32][32]          16,384
//   71721472  Wxc_bf16 [65536][2112]       276,824,064
// ---------------------------------------------------------------------------

typedef float    f32x4  __attribute__((ext_vector_type(4)));
typedef __bf16   bf16x8 __attribute__((ext_vector_type(8)));
typedef uint16_t u16;
typedef uint16_t u16x8  __attribute__((ext_vector_type(8)));
typedef uint32_t u32x2  __attribute__((ext_vector_type(2)));
typedef uint32_t u32x4  __attribute__((ext_vector_type(4)));

#define WS_XB     0
#define WS_WC     67108864
#define WS_BIAS   69337088
#define WS_U      69345792
#define WS_BW     71442944
#define WS_P      71508480
#define WS_HBUF   71574016
#define WS_MBOX   71705088
#define WS_WXC    71721472

#define OUT_H     33554432
#define OUT_C     33587200

__device__ __forceinline__ u16 f2bf(float f) {
  uint32_t u = __builtin_bit_cast(uint32_t, f);
  u = (u + 0x7fffu + ((u >> 16) & 1u)) >> 16;
  return (u16)u;
}
__device__ __forceinline__ float bf2f(u16 b) {
  uint32_t u = ((uint32_t)b) << 16;
  return __builtin_bit_cast(float, u);
}
__device__ __forceinline__ f32x4 mfma16(u16x8 a, u16x8 b, f32x4 c) {
  return __builtin_amdgcn_mfma_f32_16x16x32_bf16(
      __builtin_bit_cast(bf16x8, a), __builtin_bit_cast(bf16x8, b), c, 0, 0, 0);
}
__device__ __forceinline__ float sigm(float x) { return 1.f / (1.f + __expf(-x)); }
__device__ __forceinline__ float tanh_fast(float x) {
  float a = fabsf(x);
  float e = __expf(2.f * a);
  float t = 1.f - 2.f / (e + 1.f);
  return x < 0.f ? -t : t;
}
// barrier ordering LDS only -- vmem (prefetches) stays in flight
__device__ __forceinline__ void lds_barrier() {
  asm volatile("s_waitcnt lgkmcnt(0)" ::: "memory");
  __builtin_amdgcn_sched_barrier(0);
  __builtin_amdgcn_s_barrier();
  __builtin_amdgcn_sched_barrier(0);
}

// ---------------- Phase A: casts ----------------
__global__ void cast_x(const float* __restrict__ x, u16* __restrict__ xb) {
  int i = blockIdx.x * 256 + threadIdx.x;
  const float4* src = (const float4*)x;
  float4 a = src[(size_t)i * 2];
  float4 b = src[(size_t)i * 2 + 1];
  u16x8 o;
  o[0] = f2bf(a.x); o[1] = f2bf(a.y); o[2] = f2bf(a.z); o[3] = f2bf(a.w);
  o[4] = f2bf(b.x); o[5] = f2bf(b.y); o[6] = f2bf(b.z); o[7] = f2bf(b.w);
  *(u16x8*)(xb + (size_t)i * 8) = o;
}

__global__ void prep(const float* __restrict__ W_w, const float* __restrict__ W_b,
                     const float* __restrict__ U_w, const float* __restrict__ U_b,
                     const float* __restrict__ A_w, const float* __restrict__ B_w,
                     const float* __restrict__ P_w,
                     u16* __restrict__ Wc, float* __restrict__ bias,
                     u16* __restrict__ Ubf, u16* __restrict__ Bwbf,
                     u16* __restrict__ Pbf, uint32_t* __restrict__ mbox) {
  const int total = 1114112 + 1048576 + 32768 + 32768 + 2176 + 4096;
  for (int i = blockIdx.x * blockDim.x + threadIdx.x; i < total;
       i += gridDim.x * blockDim.x) {
    int idx = i;
    if (idx < 1114112) {                            // Wc [2176][512]
      int row = idx >> 9, k = idx & 511;
      float v = 0.f;
      if (row < 2048) v = W_w[row * 512 + k];
      else if (row < 2112) v = A_w[(row - 2048) * 512 + k];
      Wc[idx] = f2bf(v);
      continue;
    }
    idx -= 1114112;
    if (idx < 1048576) { Ubf[idx] = f2bf(U_w[idx]); continue; }
    idx -= 1048576;
    if (idx < 32768) { Bwbf[idx] = f2bf(B_w[idx]); continue; }
    idx -= 32768;
    if (idx < 32768) { Pbf[idx] = f2bf(0.1f * P_w[idx]); continue; }
    idx -= 32768;
    if (idx < 2176) {
      bias[idx] = (idx < 2048) ? (W_b[idx] + U_b[idx]) : 0.f;
      continue;
    }
    idx -= 2176;
    mbox[idx] = 0;                                  // epochs (monotone >=)
  }
}

// ---------------- Phase A: big GEMM ----------------
__global__ void __launch_bounds__(256) gemm_wxc(const u16* __restrict__ xb,
                                                const u16* __restrict__ Wc,
                                                const float* __restrict__ bias,
                                                u16* __restrict__ outWx) {
  __shared__ u16 Atile[128 * 64];
  __shared__ u16 Btile[128 * 64];
  const int n0 = blockIdx.x * 128;
  const int m0 = blockIdx.y * 128;
  const int tid = threadIdx.x, ln = tid & 63, wv = tid >> 6;
  const int wm = (wv >> 1) * 64, wn = (wv & 1) * 64;
  f32x4 acc[4][4] = {};

  for (int k0 = 0; k0 < 512; k0 += 64) {
    __syncthreads();
    #pragma unroll
    for (int q = 0; q < 4; ++q) {
      int idx = tid + q * 256;
      int row = idx >> 3, kc = idx & 7;
      uint4 va = *(const uint4*)(xb + (size_t)(m0 + row) * 512 + k0 + kc * 8);
      *(uint4*)((char*)Atile + row * 128 + ((kc * 16) ^ ((row & 7) << 4))) = va;
      uint4 vb = *(const uint4*)(Wc + (size_t)(n0 + row) * 512 + k0 + kc * 8);
      *(uint4*)((char*)Btile + row * 128 + ((kc * 16) ^ ((row & 7) << 4))) = vb;
    }
    __syncthreads();
    #pragma unroll
    for (int kk = 0; kk < 64; kk += 32) {
      u16x8 af[4], bf[4];
      const int kb = kk * 2 + ((ln >> 4) << 4);
      #pragma unroll
      for (int i = 0; i < 4; ++i) {
        int arow = wm + i * 16 + (ln & 15);
        af[i] = *(const u16x8*)((char*)Atile + arow * 128 + (kb ^ ((arow & 7) << 4)));
        int brow = wn + i * 16 + (ln & 15);
        bf[i] = *(const u16x8*)((char*)Btile + brow * 128 + (kb ^ ((brow & 7) << 4)));
      }
      #pragma unroll
      for (int i = 0; i < 4; ++i)
        #pragma unroll
        for (int j = 0; j < 4; ++j)
          acc[i][j] = mfma16(af[i], bf[j], acc[i][j]);
    }
  }
  #pragma unroll
  for (int i = 0; i < 4; ++i) {
    const int mrow = m0 + wm + i * 16 + ((ln >> 4) << 2);
    #pragma unroll
    for (int j = 0; j < 4; ++j) {
      const int n = n0 + wn + j * 16 + (ln & 15);
      if (n < 2112) {
        const float bv = bias[n];
        #pragma unroll
        for (int r = 0; r < 4; ++r)
          outWx[(size_t)(mrow + r) * 2112 + n] = f2bf(acc[i][j][r] + bv);
      }
    }
  }
}

// ---------------- Phase B: persistent recurrence ----------------
__global__ void __launch_bounds__(512, 2) recurrent(const u16* __restrict__ Wxc,
                                                    const u16* __restrict__ Ubf,
                                                    const u16* __restrict__ Bwbf,
                                                    const u16* __restrict__ Pbf,
                                                    u16* __restrict__ hbuf,
                                                    uint32_t* __restrict__ mbox,
                                                    float* __restrict__ out) {
  __shared__ char  h_lds[16 * 1024];     // [16 batches][512] bf16, swizzled
  __shared__ float v_buf[16 * 68];       // [16 batches][64 r (+4 pad)]
  __shared__ float g_buf[4 * 16 * 17];   // [4 gates][16 batches][16 u (+1)]
  __shared__ u16   hpub[16 * 16];        // producer transpose [16 b][16 u]
  __shared__ int   poll_done;            // epoch observed (monotone)

  const int tid = threadIdx.x;
  const int wv = tid >> 6, ln = tid & 63;
  const int grp = blockIdx.x & 3;        // 4 groups x 16 batches
  const int ublk = blockIdx.x >> 2;      // 32 unit-blocks x 16 units
  const int u0 = ublk << 4, b0 = grp << 4;

  uint32_t* mb_grp = mbox + grp * 32 * 32;

  // persistent B-operand fragments (loaded once)
  u16x8 bfrag[16];
  {
    const u16* src = (wv < 4)
        ? (Ubf + (size_t)(wv * 512 + u0 + (ln & 15)) * 512)
        : (Bwbf + (size_t)((wv - 4) * 16 + (ln & 15)) * 512);
    #pragma unroll
    for (int ks = 0; ks < 16; ++ks)
      bfrag[ks] = *(const u16x8*)(src + ks * 32 + ((ln >> 4) << 3));
  }
  u16x8 pfrag[2];
  #pragma unroll
  for (int ks = 0; ks < 2; ++ks)
    pfrag[ks] = *(const u16x8*)(Pbf + (size_t)(u0 + (ln & 15)) * 64 + ks * 32 + ((ln >> 4) << 3));

  for (int i = tid; i < 1024; i += 512)
    ((u32x4*)h_lds)[i] = (u32x4){0u, 0u, 0u, 0u};
  if (tid == 0) poll_done = 0;
  __syncthreads();

  const int arow_base = (ln & 15) * 1024;
  const int a_xor = (ln & 7) << 4;
  const int a_k0 = (ln >> 4) << 4;
  // reload mapping: thread covers producer-block blk's 16 units for batch b
  const int r_blk = tid >> 4, r_b = tid & 15;

  // one-step-ahead register prefetch state (batch = b0 + (ln>>4)*4 + j)
  uint32_t wx_cur[4] = {0, 0, 0, 0};
  u16x8 ax0_cur = {}, ax1_cur = {};
  {
    if (wv < 4) {
      const int col = wv * 512 + u0 + (ln & 15);
      const size_t rb = ((size_t)(b0 + ((ln >> 4) << 2)) * 1024 + 0) * 2112;
      #pragma unroll
      for (int j = 0; j < 4; ++j) wx_cur[j] = Wxc[rb + (size_t)j * 1024 * 2112 + col];
    }
    if (wv == 0) {
      const u16* axp = Wxc + ((size_t)(b0 + (ln & 15)) * 1024 + 0) * 2112 + 2048 + ((ln >> 4) << 3);
      ax0_cur = *(const u16x8*)(axp);
      ax1_cur = *(const u16x8*)(axp + 32);
    }
  }

  float c_reg[4] = {0.f, 0.f, 0.f, 0.f};
  float h_last[4] = {0.f, 0.f, 0.f, 0.f};

  #pragma unroll 1
  for (int t = 0; t < 1024; ++t) {
    // phase 1: K-loop MFMA; A = h_t [16x512] from LDS
    f32x4 acc0 = {0.f, 0.f, 0.f, 0.f}, acc1 = {0.f, 0.f, 0.f, 0.f};
    #pragma unroll
    for (int ks = 0; ks < 16; ks += 2) {
      u16x8 a0 = *(const u16x8*)(h_lds + arow_base + ((ks * 64 + a_k0) ^ a_xor));
      u16x8 a1 = *(const u16x8*)(h_lds + arow_base + (((ks + 1) * 64 + a_k0) ^ a_xor));
      acc0 = mfma16(a0, bfrag[ks], acc0);
      acc1 = mfma16(a1, bfrag[ks + 1], acc1);
    }
    const f32x4 acc = acc0 + acc1;

    // phase 2: v / gates to LDS
    if (wv >= 4) {
      const int r = ((wv - 4) << 4) + (ln & 15);
      const int br = (ln >> 4) << 2;
      #pragma unroll
      for (int j = 0; j < 4; ++j) v_buf[(br + j) * 68 + r] = acc[j];
    } else {
      const int gi = wv * 272 + (ln & 15);
      const int br = (ln >> 4) << 2;
      #pragma unroll
      for (int j = 0; j < 4; ++j) {
        float g = acc[j] + bf2f((u16)wx_cur[j]);
        g = (wv == 3) ? tanh_fast(g) : sigm(g);
        g_buf[gi + (br + j) * 17] = g;
      }
    }
    lds_barrier();                         // B1

    // phase 3 (wave 0): mix MFMA + cell update + coalesced publish + mailbox
    if (wv == 0) {
      __builtin_amdgcn_s_setprio(1);
      f32x4 accm = {0.f, 0.f, 0.f, 0.f};
      const int bb = ln & 15;
      const int r0 = (ln >> 4) << 3;
      u16x8 af;
      #pragma unroll
      for (int i = 0; i < 8; ++i)
        af[i] = f2bf(bf2f(ax0_cur[i]) * v_buf[bb * 68 + r0 + i]);
      accm = mfma16(af, pfrag[0], accm);
      #pragma unroll
      for (int i = 0; i < 8; ++i)
        af[i] = f2bf(bf2f(ax1_cur[i]) * v_buf[bb * 68 + 32 + r0 + i]);
      accm = mfma16(af, pfrag[1], accm);
      // accm[j] = mix[batch=(ln>>4)*4+j][unit=ln&15] -- register-aligned
      const int u = ln & 15;
      const int brb = (ln >> 4) * 4;
      float hv[4];
      #pragma unroll
      for (int j = 0; j < 4; ++j) {
        const int go = (brb + j) * 17 + u;
        float iv = g_buf[go];
        float fv = g_buf[272 + go];
        float ov = g_buf[544 + go];
        float gv = g_buf[816 + go];
        c_reg[j] = fv * c_reg[j] + iv * gv + accm[j];   // 0.1 folded into P
        hv[j] = ov * tanh_fast(c_reg[j]);
        h_last[j] = hv[j];
      }
      if (t < 1023) {
        #pragma unroll
        for (int j = 0; j < 4; ++j)
          hpub[(brb + j) * 16 + u] = f2bf(hv[j]);
        asm volatile("s_waitcnt lgkmcnt(0)" ::: "memory");
        __builtin_amdgcn_sched_barrier(0);
        if (ln < 32) {
          u32x4 pv = *(const u32x4*)((const char*)hpub + ln * 16);
          u16* dst = hbuf + ((size_t)(((t & 1) * 4 + grp) * 32 + ublk)) * 256 + ln * 8;
          asm volatile("global_store_dwordx4 %0, %1, off sc1"
                       :: "v"(dst), "v"(pv) : "memory");
        }
        asm volatile("s_waitcnt vmcnt(0)" ::: "memory");  // h at coherence point
        if (ln < 32)
          __hip_atomic_store(mb_grp + ln * 32 + ublk, (uint32_t)(t + 1),
                             __ATOMIC_RELAXED, __HIP_MEMORY_SCOPE_AGENT);
      }
      __builtin_amdgcn_s_setprio(0);
      #pragma unroll
      for (int j = 0; j < 4; ++j)                         // outs off crit path
        out[((size_t)(b0 + brb + j) * 1024 + t) * 512 + u0 + u] = hv[j];
    }

    // phase 4: waves 1-3 poll own mailbox line; LDS epoch early-exit
    if (wv >= 1 && wv <= 3 && t < 1023) {
      volatile int* dsf = &poll_done;
      uint32_t* fp = mb_grp + ublk * 32 + (ln & 31);
      const int target = t + 1;
      while (true) {
        if (*dsf >= target) break;
        uint32_t f = __hip_atomic_load(fp, __ATOMIC_RELAXED, __HIP_MEMORY_SCOPE_AGENT);
        if (__ballot((int)f >= target) == ~0ull) {
          if (ln == 0) *dsf = target;
          break;
        }
      }
    }
    lds_barrier();                         // B2 (h_t confirmed at IC)

    if (t < 1023) {
      // phase 5: coalesced reload (block-major) -> swizzled LDS
      const u16* src = hbuf + ((size_t)(((t & 1) * 4 + grp) * 32 + r_blk)) * 256 + r_b * 16;
      u32x4 A, B;
      asm volatile(
          "global_load_dwordx4 %0, %2, off sc1\n\t"
          "global_load_dwordx4 %1, %2, off offset:16 sc1\n\t"
          "s_waitcnt vmcnt(0)"
          : "=&v"(A), "=&v"(B) : "v"(src) : "memory");
      __builtin_amdgcn_sched_barrier(0);
      {
        const int base = r_blk * 32;
        const int xorb = (r_b & 7) << 4;
        u32x2 w;
        w[0] = A[0]; w[1] = A[1];
        *(u32x2*)(h_lds + r_b * 1024 + ((base + 0) ^ xorb)) = w;
        w[0] = A[2]; w[1] = A[3];
        *(u32x2*)(h_lds + r_b * 1024 + ((base + 8) ^ xorb)) = w;
        w[0] = B[0]; w[1] = B[1];
        *(u32x2*)(h_lds + r_b * 1024 + ((base + 16) ^ xorb)) = w;
        w[0] = B[2]; w[1] = B[3];
        *(u32x2*)(h_lds + r_b * 1024 + ((base + 24) ^ xorb)) = w;
      }
      // phase 6: prefetch Wx/Ax for t+1 AFTER the reload wait -- stays in
      // flight across B3 and retires under next phase-1 MFMA.
      if (wv < 4) {
        const int col = wv * 512 + u0 + (ln & 15);
        const size_t rb = ((size_t)(b0 + ((ln >> 4) << 2)) * 1024 + t + 1) * 2112;
        #pragma unroll
        for (int j = 0; j < 4; ++j) wx_cur[j] = Wxc[rb + (size_t)j * 1024 * 2112 + col];
      }
      if (wv == 0) {
        const u16* axp = Wxc + ((size_t)(b0 + (ln & 15)) * 1024 + t + 1) * 2112 + 2048 + ((ln >> 4) << 3);
        ax0_cur = *(const u16x8*)(axp);
        ax1_cur = *(const u16x8*)(axp + 32);
      }
    }
    lds_barrier();                         // B3
  }

  if (wv == 0) {
    const int u = ln & 15, brb = (ln >> 4) * 4;
    #pragma unroll
    for (int j = 0; j < 4; ++j) {
      out[OUT_H + (size_t)(b0 + brb + j) * 512 + u0 + u] = h_last[j];
      out[OUT_C + (size_t)(b0 + brb + j) * 512 + u0 + u] = c_reg[j];
    }
  }
}

// ---------------------------------------------------------------------------
extern "C" void kernel_launch(void* const* d_in, const int* in_sizes, int n_in,
                              void* d_out, int out_size, void* d_ws, size_t ws_size,
                              hipStream_t stream) {
  const float* x   = (const float*)d_in[0];
  const float* W_w = (const float*)d_in[1];
  const float* W_b = (const float*)d_in[2];
  const float* U_w = (const float*)d_in[3];
  const float* U_b = (const float*)d_in[4];
  const float* A_w = (const float*)d_in[5];
  const float* B_w = (const float*)d_in[6];
  const float* P_w = (const float*)d_in[7];
  char* ws = (char*)d_ws;

  u16*      xb   = (u16*)(ws + WS_XB);
  u16*      Wc   = (u16*)(ws + WS_WC);
  float*    bias = (float*)(ws + WS_BIAS);
  u16*      Ubf  = (u16*)(ws + WS_U);
  u16*      Bwbf = (u16*)(ws + WS_BW);
  u16*      Pbf  = (u16*)(ws + WS_P);
  u16*      hbuf = (u16*)(ws + WS_HBUF);
  uint32_t* mbox = (uint32_t*)(ws + WS_MBOX);
  u16*      Wxc  = (u16*)(ws + WS_WXC);
  float*    outp = (float*)d_out;

  cast_x<<<16384, 256, 0, stream>>>(x, xb);
  prep<<<2048, 256, 0, stream>>>(W_w, W_b, U_w, U_b, A_w, B_w, P_w,
                                 Wc, bias, Ubf, Bwbf, Pbf, mbox);
  gemm_wxc<<<dim3(17, 512), 256, 0, stream>>>(xb, Wc, bias, Wxc);

  void* args[] = { &Wxc, &Ubf, &Bwbf, &Pbf, &hbuf, &mbox, &outp };
  hipError_t e = hipLaunchCooperativeKernel((const void*)recurrent, dim3(128),
                                            dim3(512), args, 0, stream);
  if (e != hipSuccess) {
    // 128 blocks / 256 CUs: co-resident even with a plain launch.
    recurrent<<<dim3(128), dim3(512), 0, stream>>>(Wxc, Ubf, Bwbf, Pbf,
                                                   hbuf, mbox, outp);
  }
}

// Round 13
// 3883.434 us; speedup vs baseline: 1.8181x; 1.0754x over previous
//
#include <hip/hip_runtime.h>
#include <stdint.h>

// ---------------------------------------------------------------------------
// mLSTM block on MI355X.
// Phase A: cast x/weights to bf16; GEMM [Wx|Ax] = x @ [W_w;A_w]^T + (W_b+U_b|0)
// Phase B: persistent recurrence: 4 groups (16 batches) x 32 blocks (16 units).
//   PUSH-NOTIFICATION protocol: producer wave publishes h (sc1 stores),
//   vmcnt(0) drain, then stores epoch t+1 into EVERY consumer's private
//   mailbox line (32 scattered dword stores, one instr). Consumer wave 1
//   polls ONLY ITS OWN 128B mailbox line (1 coalesced read) -> no read queue
//   on anyone else's store target. (Rounds 4/8 showed store-behind-poll-queue
//   at the coherence point is the dominant cost; this removes it.)
//   lds_barrier (lgkmcnt-only s_barrier) keeps Wx/Ax register prefetches in
//   flight across barriers (vs __syncthreads' vmcnt(0) drain).
//   Monotone >= epochs + parity double-buffer + prep re-zero => replay-safe.
//   [Round 12's coalesced-publish/3-wave-poll bundle regressed via +23% LDS
//   bank conflicts on the wave-0 path -- reverted to this proven round-9 form.]
// ws layout (bytes):
//   0         x_bf16   [65536][512]        67,108,864
//   67108864  Wc_bf16  [2176][512]          2,228,224
//   69337088  bias     [2176] f32               8,704
//   69345792  U_bf16   [2048][512]          2,097,152
//   71442944  Bw_bf16  [64][512]               65,536
//   71508480  P_bf16   [512][64] (x0.1)        65,536
//   71574016  hbuf     [2][64][512] bf16      131,072
//   71705088  mbox     u32[4][32][32]          16,384
//   71721472  Wxc_bf16 [65536][2112]       276,824,064
// ---------------------------------------------------------------------------

typedef float    f32x4  __attribute__((ext_vector_type(4)));
typedef __bf16   bf16x8 __attribute__((ext_vector_type(8)));
typedef uint16_t u16;
typedef uint16_t u16x8  __attribute__((ext_vector_type(8)));
typedef uint32_t u32x4  __attribute__((ext_vector_type(4)));

#define WS_XB     0
#define WS_WC     67108864
#define WS_BIAS   69337088
#define WS_U      69345792
#define WS_BW     71442944
#define WS_P      71508480
#define WS_HBUF   71574016
#define WS_MBOX   71705088
#define WS_WXC    71721472

#define OUT_H     33554432
#define OUT_C     33587200

__device__ __forceinline__ u16 f2bf(float f) {
  uint32_t u = __builtin_bit_cast(uint32_t, f);
  u = (u + 0x7fffu + ((u >> 16) & 1u)) >> 16;
  return (u16)u;
}
__device__ __forceinline__ float bf2f(u16 b) {
  uint32_t u = ((uint32_t)b) << 16;
  return __builtin_bit_cast(float, u);
}
__device__ __forceinline__ f32x4 mfma16(u16x8 a, u16x8 b, f32x4 c) {
  return __builtin_amdgcn_mfma_f32_16x16x32_bf16(
      __builtin_bit_cast(bf16x8, a), __builtin_bit_cast(bf16x8, b), c, 0, 0, 0);
}
__device__ __forceinline__ float sigm(float x) { return 1.f / (1.f + __expf(-x)); }
__device__ __forceinline__ float tanh_fast(float x) {
  float a = fabsf(x);
  float e = __expf(2.f * a);
  float t = 1.f - 2.f / (e + 1.f);
  return x < 0.f ? -t : t;
}
// barrier ordering LDS only -- vmem (prefetches) stays in flight
__device__ __forceinline__ void lds_barrier() {
  asm volatile("s_waitcnt lgkmcnt(0)" ::: "memory");
  __builtin_amdgcn_sched_barrier(0);
  __builtin_amdgcn_s_barrier();
  __builtin_amdgcn_sched_barrier(0);
}

// ---------------- Phase A: casts ----------------
__global__ void cast_x(const float* __restrict__ x, u16* __restrict__ xb) {
  int i = blockIdx.x * 256 + threadIdx.x;
  const float4* src = (const float4*)x;
  float4 a = src[(size_t)i * 2];
  float4 b = src[(size_t)i * 2 + 1];
  u16x8 o;
  o[0] = f2bf(a.x); o[1] = f2bf(a.y); o[2] = f2bf(a.z); o[3] = f2bf(a.w);
  o[4] = f2bf(b.x); o[5] = f2bf(b.y); o[6] = f2bf(b.z); o[7] = f2bf(b.w);
  *(u16x8*)(xb + (size_t)i * 8) = o;
}

__global__ void prep(const float* __restrict__ W_w, const float* __restrict__ W_b,
                     const float* __restrict__ U_w, const float* __restrict__ U_b,
                     const float* __restrict__ A_w, const float* __restrict__ B_w,
                     const float* __restrict__ P_w,
                     u16* __restrict__ Wc, float* __restrict__ bias,
                     u16* __restrict__ Ubf, u16* __restrict__ Bwbf,
                     u16* __restrict__ Pbf, uint32_t* __restrict__ mbox) {
  const int total = 1114112 + 1048576 + 32768 + 32768 + 2176 + 4096;
  for (int i = blockIdx.x * blockDim.x + threadIdx.x; i < total;
       i += gridDim.x * blockDim.x) {
    int idx = i;
    if (idx < 1114112) {                            // Wc [2176][512]
      int row = idx >> 9, k = idx & 511;
      float v = 0.f;
      if (row < 2048) v = W_w[row * 512 + k];
      else if (row < 2112) v = A_w[(row - 2048) * 512 + k];
      Wc[idx] = f2bf(v);
      continue;
    }
    idx -= 1114112;
    if (idx < 1048576) { Ubf[idx] = f2bf(U_w[idx]); continue; }
    idx -= 1048576;
    if (idx < 32768) { Bwbf[idx] = f2bf(B_w[idx]); continue; }
    idx -= 32768;
    if (idx < 32768) { Pbf[idx] = f2bf(0.1f * P_w[idx]); continue; }
    idx -= 32768;
    if (idx < 2176) {
      bias[idx] = (idx < 2048) ? (W_b[idx] + U_b[idx]) : 0.f;
      continue;
    }
    idx -= 2176;
    mbox[idx] = 0;                                  // epochs (monotone >=)
  }
}

// ---------------- Phase A: big GEMM ----------------
__global__ void __launch_bounds__(256) gemm_wxc(const u16* __restrict__ xb,
                                                const u16* __restrict__ Wc,
                                                const float* __restrict__ bias,
                                                u16* __restrict__ outWx) {
  __shared__ u16 Atile[128 * 64];
  __shared__ u16 Btile[128 * 64];
  const int n0 = blockIdx.x * 128;
  const int m0 = blockIdx.y * 128;
  const int tid = threadIdx.x, ln = tid & 63, wv = tid >> 6;
  const int wm = (wv >> 1) * 64, wn = (wv & 1) * 64;
  f32x4 acc[4][4] = {};

  for (int k0 = 0; k0 < 512; k0 += 64) {
    __syncthreads();
    #pragma unroll
    for (int q = 0; q < 4; ++q) {
      int idx = tid + q * 256;
      int row = idx >> 3, kc = idx & 7;
      uint4 va = *(const uint4*)(xb + (size_t)(m0 + row) * 512 + k0 + kc * 8);
      *(uint4*)((char*)Atile + row * 128 + ((kc * 16) ^ ((row & 7) << 4))) = va;
      uint4 vb = *(const uint4*)(Wc + (size_t)(n0 + row) * 512 + k0 + kc * 8);
      *(uint4*)((char*)Btile + row * 128 + ((kc * 16) ^ ((row & 7) << 4))) = vb;
    }
    __syncthreads();
    #pragma unroll
    for (int kk = 0; kk < 64; kk += 32) {
      u16x8 af[4], bf[4];
      const int kb = kk * 2 + ((ln >> 4) << 4);
      #pragma unroll
      for (int i = 0; i < 4; ++i) {
        int arow = wm + i * 16 + (ln & 15);
        af[i] = *(const u16x8*)((char*)Atile + arow * 128 + (kb ^ ((arow & 7) << 4)));
        int brow = wn + i * 16 + (ln & 15);
        bf[i] = *(const u16x8*)((char*)Btile + brow * 128 + (kb ^ ((brow & 7) << 4)));
      }
      #pragma unroll
      for (int i = 0; i < 4; ++i)
        #pragma unroll
        for (int j = 0; j < 4; ++j)
          acc[i][j] = mfma16(af[i], bf[j], acc[i][j]);
    }
  }
  #pragma unroll
  for (int i = 0; i < 4; ++i) {
    const int mrow = m0 + wm + i * 16 + ((ln >> 4) << 2);
    #pragma unroll
    for (int j = 0; j < 4; ++j) {
      const int n = n0 + wn + j * 16 + (ln & 15);
      if (n < 2112) {
        const float bv = bias[n];
        #pragma unroll
        for (int r = 0; r < 4; ++r)
          outWx[(size_t)(mrow + r) * 2112 + n] = f2bf(acc[i][j][r] + bv);
      }
    }
  }
}

// ---------------- Phase B: persistent recurrence ----------------
__global__ void __launch_bounds__(512, 2) recurrent(const u16* __restrict__ Wxc,
                                                    const u16* __restrict__ Ubf,
                                                    const u16* __restrict__ Bwbf,
                                                    const u16* __restrict__ Pbf,
                                                    u16* __restrict__ hbuf,
                                                    uint32_t* __restrict__ mbox,
                                                    float* __restrict__ out) {
  __shared__ char  h_lds[16 * 1024];     // [16 batches][512] bf16, swizzled
  __shared__ float v_buf[16 * 68];       // [16 batches][64 r (+4 pad)]
  __shared__ float g_buf[4 * 16 * 17];   // [4 gates][16 batches][16 u (+1)]

  const int tid = threadIdx.x;
  const int wv = tid >> 6, ln = tid & 63;
  const int grp = blockIdx.x & 3;        // 4 groups x 16 batches
  const int ublk = blockIdx.x >> 2;      // 32 unit-blocks x 16 units
  const int u0 = ublk << 4, b0 = grp << 4;

  // mailboxes: mbox[grp][consumer 0..31][producer 0..31]
  uint32_t* mb_grp = mbox + grp * 32 * 32;
  uint32_t* my_line = mb_grp + ublk * 32;          // this block's own line

  // persistent B-operand fragments (loaded once)
  u16x8 bfrag[16];
  {
    const u16* src = (wv < 4)
        ? (Ubf + (size_t)(wv * 512 + u0 + (ln & 15)) * 512)
        : (Bwbf + (size_t)((wv - 4) * 16 + (ln & 15)) * 512);
    #pragma unroll
    for (int ks = 0; ks < 16; ++ks)
      bfrag[ks] = *(const u16x8*)(src + ks * 32 + ((ln >> 4) << 3));
  }
  u16x8 pfrag[2];
  #pragma unroll
  for (int ks = 0; ks < 2; ++ks)
    pfrag[ks] = *(const u16x8*)(Pbf + (size_t)(u0 + (ln & 15)) * 64 + ks * 32 + ((ln >> 4) << 3));

  for (int i = tid; i < 1024; i += 512)
    ((u32x4*)h_lds)[i] = (u32x4){0u, 0u, 0u, 0u};
  __syncthreads();

  const int arow_base = (ln & 15) * 1024;
  const int a_xor = (ln & 7) << 4;
  const int a_k0 = (ln >> 4) << 4;

  // one-step-ahead register prefetch state (batch = b0 + (ln>>4)*4 + j)
  uint32_t wx_cur[4] = {0, 0, 0, 0};
  u16x8 ax0_cur = {}, ax1_cur = {};
  {
    if (wv < 4) {
      const int col = wv * 512 + u0 + (ln & 15);
      const size_t rb = ((size_t)(b0 + ((ln >> 4) << 2)) * 1024 + 0) * 2112;
      #pragma unroll
      for (int j = 0; j < 4; ++j) wx_cur[j] = Wxc[rb + (size_t)j * 1024 * 2112 + col];
    }
    if (wv == 0) {
      const u16* axp = Wxc + ((size_t)(b0 + (ln & 15)) * 1024 + 0) * 2112 + 2048 + ((ln >> 4) << 3);
      ax0_cur = *(const u16x8*)(axp);
      ax1_cur = *(const u16x8*)(axp + 32);
    }
  }

  float c_reg[4] = {0.f, 0.f, 0.f, 0.f};
  float h_last[4] = {0.f, 0.f, 0.f, 0.f};

  #pragma unroll 1
  for (int t = 0; t < 1024; ++t) {
    // phase 1: K-loop MFMA; A = h_t [16x512] from LDS
    f32x4 acc0 = {0.f, 0.f, 0.f, 0.f}, acc1 = {0.f, 0.f, 0.f, 0.f};
    #pragma unroll
    for (int ks = 0; ks < 16; ks += 2) {
      u16x8 a0 = *(const u16x8*)(h_lds + arow_base + ((ks * 64 + a_k0) ^ a_xor));
      u16x8 a1 = *(const u16x8*)(h_lds + arow_base + (((ks + 1) * 64 + a_k0) ^ a_xor));
      acc0 = mfma16(a0, bfrag[ks], acc0);
      acc1 = mfma16(a1, bfrag[ks + 1], acc1);
    }
    const f32x4 acc = acc0 + acc1;

    // phase 2: v / gates to LDS
    if (wv >= 4) {
      const int r = ((wv - 4) << 4) + (ln & 15);
      const int br = (ln >> 4) << 2;
      #pragma unroll
      for (int j = 0; j < 4; ++j) v_buf[(br + j) * 68 + r] = acc[j];
    } else {
      const int gi = wv * 272 + (ln & 15);
      const int br = (ln >> 4) << 2;
      #pragma unroll
      for (int j = 0; j < 4; ++j) {
        float g = acc[j] + bf2f((u16)wx_cur[j]);
        g = (wv == 3) ? tanh_fast(g) : sigm(g);
        g_buf[gi + (br + j) * 17] = g;
      }
    }
    lds_barrier();                         // B1

    // phase 3 (wave 0): mix MFMA + cell update + publish + mailbox push
    if (wv == 0) {
      __builtin_amdgcn_s_setprio(1);
      f32x4 accm = {0.f, 0.f, 0.f, 0.f};
      const int bb = ln & 15;
      const int r0 = (ln >> 4) << 3;
      u16x8 af;
      #pragma unroll
      for (int i = 0; i < 8; ++i)
        af[i] = f2bf(bf2f(ax0_cur[i]) * v_buf[bb * 68 + r0 + i]);
      accm = mfma16(af, pfrag[0], accm);
      #pragma unroll
      for (int i = 0; i < 8; ++i)
        af[i] = f2bf(bf2f(ax1_cur[i]) * v_buf[bb * 68 + 32 + r0 + i]);
      accm = mfma16(af, pfrag[1], accm);
      // accm[j] = mix[batch=(ln>>4)*4+j][unit=ln&15] -- register-aligned
      const int u = ln & 15;
      const int brb = (ln >> 4) * 4;
      u16* hdst = hbuf + (size_t)(t & 1) * 32768;
      float hv[4];
      #pragma unroll
      for (int j = 0; j < 4; ++j) {
        const int go = (brb + j) * 17 + u;
        float iv = g_buf[go];
        float fv = g_buf[272 + go];
        float ov = g_buf[544 + go];
        float gv = g_buf[816 + go];
        c_reg[j] = fv * c_reg[j] + iv * gv + accm[j];   // 0.1 folded into P
        hv[j] = ov * tanh_fast(c_reg[j]);
        h_last[j] = hv[j];
        __hip_atomic_store(hdst + (size_t)(b0 + brb + j) * 512 + u0 + u,
                           f2bf(hv[j]), __ATOMIC_RELAXED, __HIP_MEMORY_SCOPE_AGENT);
      }
      asm volatile("s_waitcnt vmcnt(0)" ::: "memory");   // h at coherence point
      // push epoch into every consumer's private mailbox line (1 store/lane)
      if (ln < 32)
        __hip_atomic_store(mb_grp + ln * 32 + ublk, (uint32_t)(t + 1),
                           __ATOMIC_RELAXED, __HIP_MEMORY_SCOPE_AGENT);
      __builtin_amdgcn_s_setprio(0);
      #pragma unroll
      for (int j = 0; j < 4; ++j)                        // outs off crit path
        out[((size_t)(b0 + brb + j) * 1024 + t) * 512 + u0 + u] = hv[j];
      // wave-0 prefetch for t+1 (in flight across barriers)
      {
        const int tn = (t < 1023) ? t + 1 : 1023;
        const u16* axp = Wxc + ((size_t)(b0 + (ln & 15)) * 1024 + tn) * 2112 + 2048 + ((ln >> 4) << 3);
        ax0_cur = *(const u16x8*)(axp);
        ax1_cur = *(const u16x8*)(axp + 32);
        const int col = u0 + (ln & 15);
        const size_t rb = ((size_t)(b0 + ((ln >> 4) << 2)) * 1024 + tn) * 2112;
        #pragma unroll
        for (int j = 0; j < 4; ++j) wx_cur[j] = Wxc[rb + (size_t)j * 1024 * 2112 + col];
      }
    } else if (wv == 1) {
      // phase 4: poll OWN mailbox line only (1 coalesced read, no contention)
      uint32_t* fp = my_line + (ln & 31);
      const uint32_t target = (uint32_t)(t + 1);
      while (true) {
        uint32_t f = __hip_atomic_load(fp, __ATOMIC_RELAXED, __HIP_MEMORY_SCOPE_AGENT);
        if (__ballot(f >= target) == ~0ull) break;
      }
      const int tn = (t < 1023) ? t + 1 : 1023;          // post-poll prefetch
      const int col = 512 + u0 + (ln & 15);
      const size_t rb = ((size_t)(b0 + ((ln >> 4) << 2)) * 1024 + tn) * 2112;
      #pragma unroll
      for (int j = 0; j < 4; ++j) wx_cur[j] = Wxc[rb + (size_t)j * 1024 * 2112 + col];
    } else if (wv < 4) {
      const int tn = (t < 1023) ? t + 1 : 1023;          // waves 2-3 prefetch
      const int col = wv * 512 + u0 + (ln & 15);
      const size_t rb = ((size_t)(b0 + ((ln >> 4) << 2)) * 1024 + tn) * 2112;
      #pragma unroll
      for (int j = 0; j < 4; ++j) wx_cur[j] = Wxc[rb + (size_t)j * 1024 * 2112 + col];
    }
    lds_barrier();                         // B2 -- wave-1 arrival gates all

    // phase 5: reload h_t [16][512] -> swizzled LDS; both sc1 loads, ONE wait
    {
      const int row0 = tid >> 6, kc = tid & 63;
      const u16* base = hbuf + (size_t)(t & 1) * 32768 + (size_t)b0 * 512 + kc * 8;
      const u16* p0 = base + (size_t)row0 * 512;
      const u16* p1 = base + (size_t)(row0 + 8) * 512;
      u32x4 v0, v1;
      asm volatile(
          "global_load_dwordx4 %0, %2, off sc1\n\t"
          "global_load_dwordx4 %1, %3, off sc1\n\t"
          "s_waitcnt vmcnt(0)"
          : "=&v"(v0), "=&v"(v1)
          : "v"(p0), "v"(p1)
          : "memory");
      *(u32x4*)(h_lds + row0 * 1024 + ((kc * 16) ^ ((row0 & 7) << 4))) = v0;
      *(u32x4*)(h_lds + (row0 + 8) * 1024 + ((kc * 16) ^ (((row0 + 8) & 7) << 4))) = v1;
    }
    lds_barrier();                         // B3
  }

  if (wv == 0) {
    const int u = ln & 15, brb = (ln >> 4) * 4;
    #pragma unroll
    for (int j = 0; j < 4; ++j) {
      out[OUT_H + (size_t)(b0 + brb + j) * 512 + u0 + u] = h_last[j];
      out[OUT_C + (size_t)(b0 + brb + j) * 512 + u0 + u] = c_reg[j];
    }
  }
}

// ---------------------------------------------------------------------------
extern "C" void kernel_launch(void* const* d_in, const int* in_sizes, int n_in,
                              void* d_out, int out_size, void* d_ws, size_t ws_size,
                              hipStream_t stream) {
  const float* x   = (const float*)d_in[0];
  const float* W_w = (const float*)d_in[1];
  const float* W_b = (const float*)d_in[2];
  const float* U_w = (const float*)d_in[3];
  const float* U_b = (const float*)d_in[4];
  const float* A_w = (const float*)d_in[5];
  const float* B_w = (const float*)d_in[6];
  const float* P_w = (const float*)d_in[7];
  char* ws = (char*)d_ws;

  u16*      xb   = (u16*)(ws + WS_XB);
  u16*      Wc   = (u16*)(ws + WS_WC);
  float*    bias = (float*)(ws + WS_BIAS);
  u16*      Ubf  = (u16*)(ws + WS_U);
  u16*      Bwbf = (u16*)(ws + WS_BW);
  u16*      Pbf  = (u16*)(ws + WS_P);
  u16*      hbuf = (u16*)(ws + WS_HBUF);
  uint32_t* mbox = (uint32_t*)(ws + WS_MBOX);
  u16*      Wxc  = (u16*)(ws + WS_WXC);
  float*    outp = (float*)d_out;

  cast_x<<<16384, 256, 0, stream>>>(x, xb);
  prep<<<2048, 256, 0, stream>>>(W_w, W_b, U_w, U_b, A_w, B_w, P_w,
                                 Wc, bias, Ubf, Bwbf, Pbf, mbox);
  gemm_wxc<<<dim3(17, 512), 256, 0, stream>>>(xb, Wc, bias, Wxc);

  void* args[] = { &Wxc, &Ubf, &Bwbf, &Pbf, &hbuf, &mbox, &outp };
  hipError_t e = hipLaunchCooperativeKernel((const void*)recurrent, dim3(128),
                                            dim3(512), args, 0, stream);
  if (e != hipSuccess) {
    // 128 blocks / 256 CUs: co-resident even with a plain launch.
    recurrent<<<dim3(128), dim3(512), 0, stream>>>(Wxc, Ubf, Bwbf, Pbf,
                                                   hbuf, mbox, outp);
  }
}